// Round 1
// baseline (443.481 us; speedup 1.0000x reference)
//
#include <hip/hip_runtime.h>
#include <stdint.h>

// Problem constants
#define B_SZ 4
#define L_SEQ 8192
#define D_CH 768
#define K_F 24
#define NFFT2 8192     // FFT size after parity split (2*4096)
#define LOGN 13

typedef __attribute__((ext_vector_type(4))) float f32x4;
typedef __attribute__((ext_vector_type(8))) __bf16 bf16x8;

// ---------- bf16 helpers (RNE) ----------
__device__ __forceinline__ uint32_t f2bf1(float f) {
  uint32_t u = __float_as_uint(f);
  return (u + 0x7fffu + ((u >> 16) & 1u)) >> 16;
}
__device__ __forceinline__ uint32_t packbf2(float lo, float hi) {
  return f2bf1(lo) | (f2bf1(hi) << 16);
}
__device__ __forceinline__ float2 unpackbf2(uint32_t v) {
  return float2{__uint_as_float(v << 16), __uint_as_float(v & 0xffff0000u)};
}
__device__ __forceinline__ float2 cmulf(float2 a, float2 b) {
  return float2{a.x * b.x - a.y * b.y, a.x * b.y + a.y * b.x};
}

// ---------- conversion kernels ----------
__global__ __launch_bounds__(256) void k_cvt_x(const float4* __restrict__ x,
                                               uint4* __restrict__ xb, int n8) {
  for (int i = blockIdx.x * 256 + threadIdx.x; i < n8; i += gridDim.x * 256) {
    float4 a = x[2 * i], b = x[2 * i + 1];
    uint4 o;
    o.x = packbf2(a.x, a.y);
    o.y = packbf2(a.z, a.w);
    o.z = packbf2(b.x, b.y);
    o.w = packbf2(b.z, b.w);
    xb[i] = o;
  }
}

// MiT[n][e] = Mi[e][n], bf16
__global__ __launch_bounds__(256) void k_mit(const float* __restrict__ Mi,
                                             uint16_t* __restrict__ MiT) {
  int i = blockIdx.x * 256 + threadIdx.x;  // = n*768 + e
  int n = i / 768, e = i - n * 768;
  MiT[i] = (uint16_t)f2bf1(Mi[e * 768 + n]);
}

// ---------- in-LDS radix-2 FFT (DIF fwd: natural->bitrev; DIT inv: bitrev->natural) ----------
__device__ void fft_dif(float2* a, int tid) {
  for (int lh = LOGN - 1; lh >= 0; --lh) {
    int h = 1 << lh;
    float winv = 1.0f / (float)(2 * h);
    __syncthreads();
    for (int j = tid; j < NFFT2 / 2; j += 256) {
      int pos = j & (h - 1);
      int i0 = ((j >> lh) << (lh + 1)) + pos;
      float2 u = a[i0], v = a[i0 + h];
      float2 s{u.x + v.x, u.y + v.y};
      float2 d{u.x - v.x, u.y - v.y};
      float sn, cs;
      __sincosf(-6.2831853071795864769f * (float)pos * winv, &sn, &cs);
      a[i0] = s;
      a[i0 + h] = float2{d.x * cs - d.y * sn, d.x * sn + d.y * cs};
    }
  }
}
__device__ void ifft_dit(float2* a, int tid) {  // unnormalized: total gain = N (folded into W2 scale)
  for (int lh = 0; lh < LOGN; ++lh) {
    int h = 1 << lh;
    float winv = 1.0f / (float)(2 * h);
    __syncthreads();
    for (int j = tid; j < NFFT2 / 2; j += 256) {
      int pos = j & (h - 1);
      int i0 = ((j >> lh) << (lh + 1)) + pos;
      float2 u = a[i0], v = a[i0 + h];
      float sn, cs;
      __sincosf(6.2831853071795864769f * (float)pos * winv, &sn, &cs);
      float2 t{v.x * cs - v.y * sn, v.x * sn + v.y * cs};
      a[i0] = float2{u.x + t.x, u.y + t.y};
      a[i0 + h] = float2{u.x - t.x, u.y - t.y};
    }
  }
}

// Phi2[k][f] = DIF-FFT( pad( (2/8192) * phi[2r, k], r<4096 ) )
__global__ __launch_bounds__(256) void k_phi(const float* __restrict__ phi,
                                             float2* __restrict__ Phi2) {
  __shared__ float2 buf[NFFT2];
  int k = blockIdx.x, tid = threadIdx.x;
  const float scale = 2.0f / 8192.0f;
  for (int r = tid; r < 4096; r += 256) {
    buf[r] = float2{phi[(2 * r) * K_F + k] * scale, 0.0f};
    buf[r + 4096] = float2{0.0f, 0.0f};
  }
  fft_dif(buf, tid);
  __syncthreads();
  for (int f = tid; f < NFFT2; f += 256) Phi2[k * NFFT2 + f] = buf[f];
}

// W2[d][f] = sum_k Mf[k][d] * Phi2[k][f]  (packed bf16 re|im)
__global__ __launch_bounds__(256) void k_w2(const float2* __restrict__ Phi2,
                                            const float* __restrict__ Mf,
                                            uint32_t* __restrict__ W2) {
  __shared__ float2 p[K_F][256];
  __shared__ float mf[K_F][32];
  int tid = threadIdx.x;
  int fc = blockIdx.x & 31, dc = blockIdx.x >> 5;
  int f0 = fc * 256, d0 = dc * 32;
  for (int i = tid; i < K_F * 256; i += 256) {
    int k = i >> 8, fl = i & 255;
    p[k][fl] = Phi2[k * NFFT2 + f0 + fl];
  }
  for (int i = tid; i < K_F * 32; i += 256) {
    int k = i >> 5, dl = i & 31;
    mf[k][dl] = Mf[k * D_CH + d0 + dl];
  }
  __syncthreads();
  for (int dl = 0; dl < 32; ++dl) {
    float re = 0.f, im = 0.f;
#pragma unroll
    for (int k = 0; k < K_F; ++k) {
      float m = mf[k][dl];
      re += m * p[k][tid].x;
      im += m * p[k][tid].y;
    }
    W2[(size_t)(d0 + dl) * NFFT2 + f0 + tid] = packbf2(re, im);
  }
}

// ---------- bf16 MFMA GEMM: Cp[b][n][t] = (x @ Mi)[m=(b,t)][n], m97-style ----------
__device__ __forceinline__ void gload_lds16(const void* g, void* l) {
  __builtin_amdgcn_global_load_lds(
      (const __attribute__((address_space(1))) void*)g,
      (__attribute__((address_space(3))) void*)l, 16, 0, 0);
}

__global__ __launch_bounds__(256) void k_gemm(const uint16_t* __restrict__ Xb,
                                              const uint16_t* __restrict__ MiT,
                                              uint16_t* __restrict__ Cp) {
  __shared__ uint16_t As[128 * 64];  // [row m][64 k] bf16, XOR-swizzled storage
  __shared__ uint16_t Bs[128 * 64];  // [row n][64 k]
  int tid = threadIdx.x;
  int lane = tid & 63, wid = tid >> 6;
  int bm = blockIdx.x / 6, bn = blockIdx.x % 6;
  int m0 = bm * 128, n0 = bn * 128;
  int wr = wid >> 1, wc = wid & 1;
  int lm = lane & 15, lg = lane >> 4;
  f32x4 acc[4][4] = {};

  for (int kt = 0; kt < 12; ++kt) {
    int k0 = kt * 64;
    __syncthreads();
#pragma unroll
    for (int it = 0; it < 4; ++it) {  // stage A: 1024 x 16B slots
      int s = it * 256 + tid;
      int row = s >> 3;
      int cb = ((s & 7) << 4) ^ ((row & 7) << 4);  // inverse-swizzled global col (bytes)
      gload_lds16(Xb + (size_t)(m0 + row) * 768 + k0 + (cb >> 1),
                  (char*)As + (it * 256 + wid * 64) * 16);
    }
#pragma unroll
    for (int it = 0; it < 4; ++it) {  // stage B
      int s = it * 256 + tid;
      int row = s >> 3;
      int cb = ((s & 7) << 4) ^ ((row & 7) << 4);
      gload_lds16(MiT + (size_t)(n0 + row) * 768 + k0 + (cb >> 1),
                  (char*)Bs + (it * 256 + wid * 64) * 16);
    }
    asm volatile("s_waitcnt vmcnt(0)" ::: "memory");
    __syncthreads();
#pragma unroll
    for (int ks = 0; ks < 2; ++ks) {
      int kbyte = (ks * 32 + lg * 8) * 2;
      bf16x8 a[4], b[4];
#pragma unroll
      for (int mi = 0; mi < 4; ++mi) {
        int row = wr * 64 + mi * 16 + lm;
        a[mi] = *(const bf16x8*)((const char*)As + row * 128 + (kbyte ^ ((row & 7) << 4)));
      }
#pragma unroll
      for (int ni = 0; ni < 4; ++ni) {
        int row = wc * 64 + ni * 16 + lm;
        b[ni] = *(const bf16x8*)((const char*)Bs + row * 128 + (kbyte ^ ((row & 7) << 4)));
      }
#pragma unroll
      for (int mi = 0; mi < 4; ++mi)
#pragma unroll
        for (int ni = 0; ni < 4; ++ni)
          acc[mi][ni] = __builtin_amdgcn_mfma_f32_16x16x32_bf16(a[mi], b[ni], acc[mi][ni], 0, 0, 0);
    }
  }
  // epilogue: D[(lg*4+r)][lm] per frag; write transposed (B,D,L) bf16, 4 t-contig per lane
#pragma unroll
  for (int mi = 0; mi < 4; ++mi) {
#pragma unroll
    for (int ni = 0; ni < 4; ++ni) {
      int mg = m0 + wr * 64 + mi * 16 + lg * 4;
      int dd = n0 + wc * 64 + ni * 16 + lm;
      int bb = mg >> 13, t = mg & 8191;
      f32x4 v = acc[mi][ni];
      uint2 o;
      o.x = packbf2(v[0], v[1]);
      o.y = packbf2(v[2], v[3]);
      *(uint2*)(Cp + ((size_t)bb * 768 + dd) * 8192 + t) = o;
    }
  }
}

// ---------- per-(b,d) FFT conv: z=row as float2 (parity pack), FFT, *W2, IFFT ----------
__global__ __launch_bounds__(256) void k_conv(const uint16_t* __restrict__ xprojT,
                                              const uint32_t* __restrict__ W2,
                                              uint16_t* __restrict__ convo) {
  __shared__ float2 buf[NFFT2];  // 64 KB
  int tid = threadIdx.x;
  int bd = blockIdx.x;  // b*768 + d
  int d = bd % 768;
  const uint4* row = (const uint4*)(xprojT + (size_t)bd * 8192);
  for (int i = tid; i < 1024; i += 256) {
    uint4 v = row[i];
    int base = i * 4;
    buf[base + 0] = unpackbf2(v.x);
    buf[base + 1] = unpackbf2(v.y);
    buf[base + 2] = unpackbf2(v.z);
    buf[base + 3] = unpackbf2(v.w);
  }
  for (int i = tid; i < 4096; i += 256) buf[4096 + i] = float2{0.f, 0.f};
  fft_dif(buf, tid);
  __syncthreads();
  const uint32_t* wrow = W2 + (size_t)d * NFFT2;
  for (int f = tid; f < NFFT2; f += 256) buf[f] = cmulf(buf[f], unpackbf2(wrow[f]));
  ifft_dit(buf, tid);
  __syncthreads();
  uint4* orow = (uint4*)(convo + (size_t)bd * 8192);
  for (int i = tid; i < 1024; i += 256) {
    int base = i * 4;
    uint4 o;
    o.x = packbf2(buf[base + 0].x, buf[base + 0].y);
    o.y = packbf2(buf[base + 1].x, buf[base + 1].y);
    o.z = packbf2(buf[base + 2].x, buf[base + 2].y);
    o.w = packbf2(buf[base + 3].x, buf[base + 3].y);
    orow[i] = o;
  }
}

// ---------- transpose (B,D,L) bf16 -> (B,L,D) fp32 ----------
__global__ __launch_bounds__(256) void k_tr(const uint16_t* __restrict__ convo,
                                            float* __restrict__ out) {
  __shared__ uint16_t tile[64][72];
  int tid = threadIdx.x;
  int bx = blockIdx.x;
  int b = bx / 1536;
  int r = bx - b * 1536;
  int d0 = (r >> 7) << 6;
  int t0 = (r & 127) << 6;
  {
    int rr = tid >> 3;
    int c8 = (tid & 7) << 3;
#pragma unroll
    for (int p = 0; p < 2; ++p) {
      int row = p * 32 + rr;
      uint4 v = *(const uint4*)(convo + ((size_t)(b * 768 + d0 + row)) * 8192 + t0 + c8);
      *(uint4*)&tile[row][c8] = v;
    }
  }
  __syncthreads();
  {
    int c4 = (tid & 15) << 2;
    int tg = tid >> 4;
#pragma unroll
    for (int p = 0; p < 4; ++p) {
      int tt = p * 16 + tg;
      float4 o;
      o.x = __uint_as_float((uint32_t)tile[c4 + 0][tt] << 16);
      o.y = __uint_as_float((uint32_t)tile[c4 + 1][tt] << 16);
      o.z = __uint_as_float((uint32_t)tile[c4 + 2][tt] << 16);
      o.w = __uint_as_float((uint32_t)tile[c4 + 3][tt] << 16);
      *(float4*)(out + ((size_t)b * 8192 + t0 + tt) * 768 + d0 + c4) = o;
    }
  }
}

extern "C" void kernel_launch(void* const* d_in, const int* in_sizes, int n_in,
                              void* d_out, int out_size, void* d_ws, size_t ws_size,
                              hipStream_t stream) {
  const float* x   = (const float*)d_in[0];
  const float* phi = (const float*)d_in[1];
  const float* Mi  = (const float*)d_in[2];
  const float* Mf  = (const float*)d_in[3];
  float* out = (float*)d_out;

  // d_out doubles as staging: [0,48MB) x bf16, [48MB,96MB) x_projT bf16 (B,D,L)
  uint16_t* xb     = (uint16_t*)d_out;
  uint16_t* xprojT = xb + 25165824;

  char* ws = (char*)d_ws;
  uint16_t* convo = (uint16_t*)ws;               // 50,331,648 B  (B,D,L) bf16 conv result
  uint32_t* W2    = (uint32_t*)(ws + 50331648);  // 25,165,824 B  [768][8192] bf16 re|im
  float2*   Phi2  = (float2*)(ws + 75497472);    //  1,572,864 B  [24][8192] fp32 complex
  uint16_t* MiT   = (uint16_t*)(ws + 77070336);  //  1,179,648 B  [768][768] bf16

  k_cvt_x<<<3072, 256, 0, stream>>>((const float4*)x, (uint4*)xb, 25165824 / 8);
  k_mit<<<2304, 256, 0, stream>>>(Mi, MiT);
  k_phi<<<24, 256, 0, stream>>>(phi, Phi2);
  k_w2<<<768, 256, 0, stream>>>(Phi2, Mf, W2);
  k_gemm<<<1536, 256, 0, stream>>>(xb, MiT, xprojT);
  k_conv<<<3072, 256, 0, stream>>>(xprojT, W2, convo);
  k_tr<<<6144, 256, 0, stream>>>(convo, out);
}

// Round 2
// 303.644 us; speedup vs baseline: 1.4605x; 1.4605x over previous
//
#include <hip/hip_runtime.h>
#include <stdint.h>

// Problem constants
#define B_SZ 4
#define L_SEQ 8192
#define D_CH 768
#define K_F 24
#define NFFT2 8192     // FFT size after parity split (2*4096)
#define LOGN 13

typedef __attribute__((ext_vector_type(4))) float f32x4;
typedef __attribute__((ext_vector_type(8))) __bf16 bf16x8;

// ---------- bf16 helpers (RNE) ----------
__device__ __forceinline__ uint32_t f2bf1(float f) {
  uint32_t u = __float_as_uint(f);
  return (u + 0x7fffu + ((u >> 16) & 1u)) >> 16;
}
__device__ __forceinline__ uint32_t packbf2(float lo, float hi) {
  return f2bf1(lo) | (f2bf1(hi) << 16);
}
__device__ __forceinline__ float2 unpackbf2(uint32_t v) {
  return float2{__uint_as_float(v << 16), __uint_as_float(v & 0xffff0000u)};
}
__device__ __forceinline__ float2 cmulf(float2 a, float2 b) {
  return float2{a.x * b.x - a.y * b.y, a.x * b.y + a.y * b.x};
}

// LDS bank swizzle on complex index: spreads small-stride FFT stages across bank pairs
__device__ __forceinline__ int SW(int i) { return i ^ ((i >> 4) & 15); }

// ---------- conversion kernels ----------
__global__ __launch_bounds__(256) void k_cvt_x(const float4* __restrict__ x,
                                               uint4* __restrict__ xb, int n8) {
  for (int i = blockIdx.x * 256 + threadIdx.x; i < n8; i += gridDim.x * 256) {
    float4 a = x[2 * i], b = x[2 * i + 1];
    uint4 o;
    o.x = packbf2(a.x, a.y);
    o.y = packbf2(a.z, a.w);
    o.z = packbf2(b.x, b.y);
    o.w = packbf2(b.z, b.w);
    xb[i] = o;
  }
}

// MiT[n][e] = Mi[e][n], bf16
__global__ __launch_bounds__(256) void k_mit(const float* __restrict__ Mi,
                                             uint16_t* __restrict__ MiT) {
  int i = blockIdx.x * 256 + threadIdx.x;  // = n*768 + e
  int n = i / 768, e = i - n * 768;
  MiT[i] = (uint16_t)f2bf1(Mi[e * 768 + n]);
}

// ---------- radix-8 DFT building block ----------
// S=-1: forward (W8 = e^{-2pi i/8}); S=+1: inverse (unnormalized, W8^{-1})
template <int S>
__device__ __forceinline__ void dft8(float2* x) {
  const float C = 0.70710678118654752f;
  float2 t0{x[0].x + x[4].x, x[0].y + x[4].y}, t1{x[0].x - x[4].x, x[0].y - x[4].y};
  float2 t2{x[2].x + x[6].x, x[2].y + x[6].y}, t3{x[2].x - x[6].x, x[2].y - x[6].y};
  float2 t4{x[1].x + x[5].x, x[1].y + x[5].y}, t5{x[1].x - x[5].x, x[1].y - x[5].y};
  float2 t6{x[3].x + x[7].x, x[3].y + x[7].y}, t7{x[3].x - x[7].x, x[3].y - x[7].y};
  float2 t3r = (S < 0) ? float2{t3.y, -t3.x} : float2{-t3.y, t3.x};
  float2 t7r = (S < 0) ? float2{t7.y, -t7.x} : float2{-t7.y, t7.x};
  float2 e0{t0.x + t2.x, t0.y + t2.y}, e2{t0.x - t2.x, t0.y - t2.y};
  float2 e1{t1.x + t3r.x, t1.y + t3r.y}, e3{t1.x - t3r.x, t1.y - t3r.y};
  float2 o0{t4.x + t6.x, t4.y + t6.y}, o2{t4.x - t6.x, t4.y - t6.y};
  float2 o1{t5.x + t7r.x, t5.y + t7r.y}, o3{t5.x - t7r.x, t5.y - t7r.y};
  float2 o1r = (S < 0) ? float2{C * (o1.x + o1.y), C * (o1.y - o1.x)}
                       : float2{C * (o1.x - o1.y), C * (o1.y + o1.x)};
  float2 o2r = (S < 0) ? float2{o2.y, -o2.x} : float2{-o2.y, o2.x};
  float2 o3r = (S < 0) ? float2{C * (o3.y - o3.x), -C * (o3.x + o3.y)}
                       : float2{-C * (o3.x + o3.y), C * (o3.x - o3.y)};
  x[0] = float2{e0.x + o0.x, e0.y + o0.y};
  x[4] = float2{e0.x - o0.x, e0.y - o0.y};
  x[1] = float2{e1.x + o1r.x, e1.y + o1r.y};
  x[5] = float2{e1.x - o1r.x, e1.y - o1r.y};
  x[2] = float2{e2.x + o2r.x, e2.y + o2r.y};
  x[6] = float2{e2.x - o2r.x, e2.y - o2r.y};
  x[3] = float2{e3.x + o3r.x, e3.y + o3r.y};
  x[7] = float2{e3.x - o3r.x, e3.y - o3r.y};
}

// ---------- in-LDS FFT: 4 radix-8 DIF passes + radix-2 (natural -> digit-reversed) ----------
__device__ void fft8_dif(float2* a, int tid, int nthr) {
#pragma unroll
  for (int lh = 10; lh >= 1; lh -= 3) {
    int h = 1 << lh;
    float ang = -6.2831853071795864769f / (float)(h * 8);
    __syncthreads();
    for (int j = tid; j < 1024; j += nthr) {
      int pos = j & (h - 1);
      int base = ((j >> lh) << (lh + 3)) + pos;
      float2 x[8];
#pragma unroll
      for (int q = 0; q < 8; ++q) x[q] = a[SW(base + q * h)];
      dft8<-1>(x);
      float sn, cs;
      __sincosf(ang * (float)pos, &sn, &cs);
      float2 w{cs, sn}, wq = w;
      x[1] = cmulf(x[1], wq);
#pragma unroll
      for (int q = 2; q < 8; ++q) {
        wq = cmulf(wq, w);
        x[q] = cmulf(x[q], wq);
      }
#pragma unroll
      for (int q = 0; q < 8; ++q) a[SW(base + q * h)] = x[q];
    }
  }
  __syncthreads();
  for (int j = tid; j < 4096; j += nthr) {
    int i0 = SW(2 * j), i1 = SW(2 * j + 1);
    float2 u = a[i0], v = a[i1];
    a[i0] = float2{u.x + v.x, u.y + v.y};
    a[i1] = float2{u.x - v.x, u.y - v.y};
  }
}

// inverse: radix-2 + 4 radix-8 DIT passes (digit-reversed -> natural), gain = 8192
__device__ void ifft8_dit(float2* a, int tid, int nthr) {
  __syncthreads();
  for (int j = tid; j < 4096; j += nthr) {
    int i0 = SW(2 * j), i1 = SW(2 * j + 1);
    float2 u = a[i0], v = a[i1];
    a[i0] = float2{u.x + v.x, u.y + v.y};
    a[i1] = float2{u.x - v.x, u.y - v.y};
  }
#pragma unroll
  for (int lh = 1; lh <= 10; lh += 3) {
    int h = 1 << lh;
    float ang = 6.2831853071795864769f / (float)(h * 8);
    __syncthreads();
    for (int j = tid; j < 1024; j += nthr) {
      int pos = j & (h - 1);
      int base = ((j >> lh) << (lh + 3)) + pos;
      float2 x[8];
#pragma unroll
      for (int q = 0; q < 8; ++q) x[q] = a[SW(base + q * h)];
      float sn, cs;
      __sincosf(ang * (float)pos, &sn, &cs);
      float2 w{cs, sn}, wq = w;
      x[1] = cmulf(x[1], wq);
#pragma unroll
      for (int q = 2; q < 8; ++q) {
        wq = cmulf(wq, w);
        x[q] = cmulf(x[q], wq);
      }
      dft8<1>(x);
#pragma unroll
      for (int q = 0; q < 8; ++q) a[SW(base + q * h)] = x[q];
    }
  }
}

// Phi2[k][f] = DIF-FFT( pad( (2/8192) * phi[2r, k], r<4096 ) ), digit-reversed order
__global__ __launch_bounds__(256) void k_phi(const float* __restrict__ phi,
                                             float2* __restrict__ Phi2) {
  __shared__ float2 buf[NFFT2];
  int k = blockIdx.x, tid = threadIdx.x;
  const float scale = 2.0f / 8192.0f;
  for (int r = tid; r < 4096; r += 256) {
    buf[SW(r)] = float2{phi[(2 * r) * K_F + k] * scale, 0.0f};
    buf[SW(r + 4096)] = float2{0.0f, 0.0f};
  }
  fft8_dif(buf, tid, 256);
  __syncthreads();
  for (int f = tid; f < NFFT2; f += 256) Phi2[k * NFFT2 + f] = buf[SW(f)];
}

// W2[d][f] = sum_k Mf[k][d] * Phi2[k][f]  (packed bf16 re|im)
__global__ __launch_bounds__(256) void k_w2(const float2* __restrict__ Phi2,
                                            const float* __restrict__ Mf,
                                            uint32_t* __restrict__ W2) {
  __shared__ float2 p[K_F][256];
  __shared__ float mf[K_F][32];
  int tid = threadIdx.x;
  int fc = blockIdx.x & 31, dc = blockIdx.x >> 5;
  int f0 = fc * 256, d0 = dc * 32;
  for (int i = tid; i < K_F * 256; i += 256) {
    int k = i >> 8, fl = i & 255;
    p[k][fl] = Phi2[k * NFFT2 + f0 + fl];
  }
  for (int i = tid; i < K_F * 32; i += 256) {
    int k = i >> 5, dl = i & 31;
    mf[k][dl] = Mf[k * D_CH + d0 + dl];
  }
  __syncthreads();
  for (int dl = 0; dl < 32; ++dl) {
    float re = 0.f, im = 0.f;
#pragma unroll
    for (int k = 0; k < K_F; ++k) {
      float m = mf[k][dl];
      re += m * p[k][tid].x;
      im += m * p[k][tid].y;
    }
    W2[(size_t)(d0 + dl) * NFFT2 + f0 + tid] = packbf2(re, im);
  }
}

// ---------- bf16 MFMA GEMM: Cp[b][n][t] = (x @ Mi)[m=(b,t)][n], m97-style ----------
__device__ __forceinline__ void gload_lds16(const void* g, void* l) {
  __builtin_amdgcn_global_load_lds(
      (const __attribute__((address_space(1))) void*)g,
      (__attribute__((address_space(3))) void*)l, 16, 0, 0);
}

__global__ __launch_bounds__(256) void k_gemm(const uint16_t* __restrict__ Xb,
                                              const uint16_t* __restrict__ MiT,
                                              uint16_t* __restrict__ Cp) {
  __shared__ uint16_t As[128 * 64];  // [row m][64 k] bf16, XOR-swizzled storage
  __shared__ uint16_t Bs[128 * 64];  // [row n][64 k]
  int tid = threadIdx.x;
  int lane = tid & 63, wid = tid >> 6;
  int bm = blockIdx.x / 6, bn = blockIdx.x % 6;
  int m0 = bm * 128, n0 = bn * 128;
  int wr = wid >> 1, wc = wid & 1;
  int lm = lane & 15, lg = lane >> 4;
  f32x4 acc[4][4] = {};

  for (int kt = 0; kt < 12; ++kt) {
    int k0 = kt * 64;
    __syncthreads();
#pragma unroll
    for (int it = 0; it < 4; ++it) {  // stage A: 1024 x 16B slots
      int s = it * 256 + tid;
      int row = s >> 3;
      int cb = ((s & 7) << 4) ^ ((row & 7) << 4);  // inverse-swizzled global col (bytes)
      gload_lds16(Xb + (size_t)(m0 + row) * 768 + k0 + (cb >> 1),
                  (char*)As + (it * 256 + wid * 64) * 16);
    }
#pragma unroll
    for (int it = 0; it < 4; ++it) {  // stage B
      int s = it * 256 + tid;
      int row = s >> 3;
      int cb = ((s & 7) << 4) ^ ((row & 7) << 4);
      gload_lds16(MiT + (size_t)(n0 + row) * 768 + k0 + (cb >> 1),
                  (char*)Bs + (it * 256 + wid * 64) * 16);
    }
    asm volatile("s_waitcnt vmcnt(0)" ::: "memory");
    __syncthreads();
#pragma unroll
    for (int ks = 0; ks < 2; ++ks) {
      int kbyte = (ks * 32 + lg * 8) * 2;
      bf16x8 a[4], b[4];
#pragma unroll
      for (int mi = 0; mi < 4; ++mi) {
        int row = wr * 64 + mi * 16 + lm;
        a[mi] = *(const bf16x8*)((const char*)As + row * 128 + (kbyte ^ ((row & 7) << 4)));
      }
#pragma unroll
      for (int ni = 0; ni < 4; ++ni) {
        int row = wc * 64 + ni * 16 + lm;
        b[ni] = *(const bf16x8*)((const char*)Bs + row * 128 + (kbyte ^ ((row & 7) << 4)));
      }
#pragma unroll
      for (int mi = 0; mi < 4; ++mi)
#pragma unroll
        for (int ni = 0; ni < 4; ++ni)
          acc[mi][ni] = __builtin_amdgcn_mfma_f32_16x16x32_bf16(a[mi], b[ni], acc[mi][ni], 0, 0, 0);
    }
  }
  // epilogue: D[(lg*4+r)][lm] per frag; write transposed (B,D,L) bf16, 4 t-contig per lane
#pragma unroll
  for (int mi = 0; mi < 4; ++mi) {
#pragma unroll
    for (int ni = 0; ni < 4; ++ni) {
      int mg = m0 + wr * 64 + mi * 16 + lg * 4;
      int dd = n0 + wc * 64 + ni * 16 + lm;
      int bb = mg >> 13, t = mg & 8191;
      f32x4 v = acc[mi][ni];
      uint2 o;
      o.x = packbf2(v[0], v[1]);
      o.y = packbf2(v[2], v[3]);
      *(uint2*)(Cp + ((size_t)bb * 768 + dd) * 8192 + t) = o;
    }
  }
}

// ---------- per-(b,d) FFT conv: z=row as float2 (parity pack), FFT, *W2, IFFT ----------
__global__ __launch_bounds__(512, 4) void k_conv(const uint16_t* __restrict__ xprojT,
                                                 const uint32_t* __restrict__ W2,
                                                 uint16_t* __restrict__ convo) {
  __shared__ float2 buf[NFFT2];  // 64 KB
  int tid = threadIdx.x;
  int bd = blockIdx.x;  // b*768 + d
  int d = bd % 768;
  const uint4* row = (const uint4*)(xprojT + (size_t)bd * 8192);
  for (int i = tid; i < 1024; i += 512) {
    uint4 v = row[i];
    int base = i * 4;
    buf[SW(base + 0)] = unpackbf2(v.x);
    buf[SW(base + 1)] = unpackbf2(v.y);
    buf[SW(base + 2)] = unpackbf2(v.z);
    buf[SW(base + 3)] = unpackbf2(v.w);
  }
  for (int i = tid; i < 4096; i += 512) buf[SW(4096 + i)] = float2{0.f, 0.f};
  fft8_dif(buf, tid, 512);
  __syncthreads();
  const uint32_t* wrow = W2 + (size_t)d * NFFT2;
  for (int f = tid; f < NFFT2; f += 512) {
    int s = SW(f);
    buf[s] = cmulf(buf[s], unpackbf2(wrow[f]));
  }
  ifft8_dit(buf, tid, 512);
  __syncthreads();
  uint4* orow = (uint4*)(convo + (size_t)bd * 8192);
  for (int i = tid; i < 1024; i += 512) {
    int base = i * 4;
    uint4 o;
    o.x = packbf2(buf[SW(base + 0)].x, buf[SW(base + 0)].y);
    o.y = packbf2(buf[SW(base + 1)].x, buf[SW(base + 1)].y);
    o.z = packbf2(buf[SW(base + 2)].x, buf[SW(base + 2)].y);
    o.w = packbf2(buf[SW(base + 3)].x, buf[SW(base + 3)].y);
    orow[i] = o;
  }
}

// ---------- transpose (B,D,L) bf16 -> (B,L,D) fp32 ----------
__global__ __launch_bounds__(256) void k_tr(const uint16_t* __restrict__ convo,
                                            float* __restrict__ out) {
  __shared__ uint16_t tile[64][72];
  int tid = threadIdx.x;
  int bx = blockIdx.x;
  int b = bx / 1536;
  int r = bx - b * 1536;
  int d0 = (r >> 7) << 6;
  int t0 = (r & 127) << 6;
  {
    int rr = tid >> 3;
    int c8 = (tid & 7) << 3;
#pragma unroll
    for (int p = 0; p < 2; ++p) {
      int row = p * 32 + rr;
      uint4 v = *(const uint4*)(convo + ((size_t)(b * 768 + d0 + row)) * 8192 + t0 + c8);
      *(uint4*)&tile[row][c8] = v;
    }
  }
  __syncthreads();
  {
    int c4 = (tid & 15) << 2;
    int tg = tid >> 4;
#pragma unroll
    for (int p = 0; p < 4; ++p) {
      int tt = p * 16 + tg;
      float4 o;
      o.x = __uint_as_float((uint32_t)tile[c4 + 0][tt] << 16);
      o.y = __uint_as_float((uint32_t)tile[c4 + 1][tt] << 16);
      o.z = __uint_as_float((uint32_t)tile[c4 + 2][tt] << 16);
      o.w = __uint_as_float((uint32_t)tile[c4 + 3][tt] << 16);
      *(float4*)(out + ((size_t)b * 8192 + t0 + tt) * 768 + d0 + c4) = o;
    }
  }
}

extern "C" void kernel_launch(void* const* d_in, const int* in_sizes, int n_in,
                              void* d_out, int out_size, void* d_ws, size_t ws_size,
                              hipStream_t stream) {
  const float* x   = (const float*)d_in[0];
  const float* phi = (const float*)d_in[1];
  const float* Mi  = (const float*)d_in[2];
  const float* Mf  = (const float*)d_in[3];
  float* out = (float*)d_out;

  // d_out doubles as staging: [0,48MB) x bf16, [48MB,96MB) x_projT bf16 (B,D,L)
  uint16_t* xb     = (uint16_t*)d_out;
  uint16_t* xprojT = xb + 25165824;

  char* ws = (char*)d_ws;
  uint16_t* convo = (uint16_t*)ws;               // 50,331,648 B  (B,D,L) bf16 conv result
  uint32_t* W2    = (uint32_t*)(ws + 50331648);  // 25,165,824 B  [768][8192] bf16 re|im
  float2*   Phi2  = (float2*)(ws + 75497472);    //  1,572,864 B  [24][8192] fp32 complex
  uint16_t* MiT   = (uint16_t*)(ws + 77070336);  //  1,179,648 B  [768][768] bf16

  k_cvt_x<<<3072, 256, 0, stream>>>((const float4*)x, (uint4*)xb, 25165824 / 8);
  k_mit<<<2304, 256, 0, stream>>>(Mi, MiT);
  k_phi<<<24, 256, 0, stream>>>(phi, Phi2);
  k_w2<<<768, 256, 0, stream>>>(Phi2, Mf, W2);
  k_gemm<<<1536, 256, 0, stream>>>(xb, MiT, xprojT);
  k_conv<<<3072, 512, 0, stream>>>(xprojT, W2, convo);
  k_tr<<<6144, 256, 0, stream>>>(convo, out);
}

// Round 3
// 253.224 us; speedup vs baseline: 1.7513x; 1.1991x over previous
//
#include <hip/hip_runtime.h>
#include <stdint.h>

// Problem constants
#define B_SZ 4
#define L_SEQ 8192
#define D_CH 768
#define K_F 24
#define NFFT2 8192     // FFT size after parity split (2*4096)
#define LDS_BYTES 69632  // 8704 float2 (padded: phi(i) = i + (i>>4))

typedef __attribute__((ext_vector_type(4))) float f32x4;
typedef __attribute__((ext_vector_type(8))) __bf16 bf16x8;

// ---------- bf16 helpers (RNE) ----------
__device__ __forceinline__ uint32_t f2bf1(float f) {
  uint32_t u = __float_as_uint(f);
  return (u + 0x7fffu + ((u >> 16) & 1u)) >> 16;
}
__device__ __forceinline__ uint32_t packbf2(float lo, float hi) {
  return f2bf1(lo) | (f2bf1(hi) << 16);
}
__device__ __forceinline__ float2 unpackbf2(uint32_t v) {
  return float2{__uint_as_float(v << 16), __uint_as_float(v & 0xffff0000u)};
}
__device__ __forceinline__ float2 cmulf(float2 a, float2 b) {
  return float2{a.x * b.x - a.y * b.y, a.x * b.y + a.y * b.x};
}
__device__ __forceinline__ uint32_t pkbf(float lo, float hi) {
  uint32_t r;
  asm("v_cvt_pk_bf16_f32 %0, %1, %2" : "=v"(r) : "v"(lo), "v"(hi));
  return r;
}

// MiT[n][e] = Mi[e][n], bf16
__global__ __launch_bounds__(256) void k_mit(const float* __restrict__ Mi,
                                             uint16_t* __restrict__ MiT) {
  int i = blockIdx.x * 256 + threadIdx.x;  // = n*768 + e
  int n = i / 768, e = i - n * 768;
  MiT[i] = (uint16_t)f2bf1(Mi[e * 768 + n]);
}

// ---------- radix-8 DFT building block ----------
// S=-1: forward (W8 = e^{-2pi i/8}); S=+1: inverse (unnormalized, W8^{-1})
template <int S>
__device__ __forceinline__ void dft8(float2* x) {
  const float C = 0.70710678118654752f;
  float2 t0{x[0].x + x[4].x, x[0].y + x[4].y}, t1{x[0].x - x[4].x, x[0].y - x[4].y};
  float2 t2{x[2].x + x[6].x, x[2].y + x[6].y}, t3{x[2].x - x[6].x, x[2].y - x[6].y};
  float2 t4{x[1].x + x[5].x, x[1].y + x[5].y}, t5{x[1].x - x[5].x, x[1].y - x[5].y};
  float2 t6{x[3].x + x[7].x, x[3].y + x[7].y}, t7{x[3].x - x[7].x, x[3].y - x[7].y};
  float2 t3r = (S < 0) ? float2{t3.y, -t3.x} : float2{-t3.y, t3.x};
  float2 t7r = (S < 0) ? float2{t7.y, -t7.x} : float2{-t7.y, t7.x};
  float2 e0{t0.x + t2.x, t0.y + t2.y}, e2{t0.x - t2.x, t0.y - t2.y};
  float2 e1{t1.x + t3r.x, t1.y + t3r.y}, e3{t1.x - t3r.x, t1.y - t3r.y};
  float2 o0{t4.x + t6.x, t4.y + t6.y}, o2{t4.x - t6.x, t4.y - t6.y};
  float2 o1{t5.x + t7r.x, t5.y + t7r.y}, o3{t5.x - t7r.x, t5.y - t7r.y};
  float2 o1r = (S < 0) ? float2{C * (o1.x + o1.y), C * (o1.y - o1.x)}
                       : float2{C * (o1.x - o1.y), C * (o1.y + o1.x)};
  float2 o2r = (S < 0) ? float2{o2.y, -o2.x} : float2{-o2.y, o2.x};
  float2 o3r = (S < 0) ? float2{C * (o3.y - o3.x), -C * (o3.x + o3.y)}
                       : float2{-C * (o3.x + o3.y), C * (o3.x - o3.y)};
  x[0] = float2{e0.x + o0.x, e0.y + o0.y};
  x[4] = float2{e0.x - o0.x, e0.y - o0.y};
  x[1] = float2{e1.x + o1r.x, e1.y + o1r.y};
  x[5] = float2{e1.x - o1r.x, e1.y - o1r.y};
  x[2] = float2{e2.x + o2r.x, e2.y + o2r.y};
  x[6] = float2{e2.x - o2r.x, e2.y - o2r.y};
  x[3] = float2{e3.x + o3r.x, e3.y + o3r.y};
  x[7] = float2{e3.x - o3r.x, e3.y - o3r.y};
}

// Generic radix-8 LDS pass on padded layout. One address compute per butterfly;
// all 16 LDS accesses use compile-time immediate offsets (stride st = h + h/16).
template <int LH, int S, int NT>
__device__ __forceinline__ void pass_r8(float2* a, int tid) {
  constexpr int h = 1 << LH;
  constexpr int st = h + (h >> 4);
  const float ang = (S < 0 ? -6.2831853071795864769f : 6.2831853071795864769f) / (float)(h * 8);
  __syncthreads();
#pragma unroll
  for (int jj = 0; jj < 1024 / NT; ++jj) {
    int j = jj * NT + tid;
    int pos = j & (h - 1);
    int base = ((j >> LH) << (LH + 3)) + pos;
    float2* p = a + (base + (base >> 4));
    float2 x[8];
#pragma unroll
    for (int q = 0; q < 8; ++q) x[q] = p[q * st];
    float sn, cs;
    __sincosf(ang * (float)pos, &sn, &cs);
    float2 w{cs, sn};
    if constexpr (S < 0) {
      dft8<-1>(x);
      float2 wq = w;
      x[1] = cmulf(x[1], wq);
#pragma unroll
      for (int q = 2; q < 8; ++q) {
        wq = cmulf(wq, w);
        x[q] = cmulf(x[q], wq);
      }
    } else {
      float2 wq = w;
      x[1] = cmulf(x[1], wq);
#pragma unroll
      for (int q = 2; q < 8; ++q) {
        wq = cmulf(wq, w);
        x[q] = cmulf(x[q], wq);
      }
      dft8<1>(x);
    }
#pragma unroll
    for (int q = 0; q < 8; ++q) p[q * st] = x[q];
  }
}

// Fused first forward pass (h=1024): read packed bf16 row from global, upper half zero.
__device__ __forceinline__ void p1_fused(float2* a, const uint32_t* __restrict__ row32, int tid) {
#pragma unroll
  for (int jj = 0; jj < 2; ++jj) {
    int j = jj * 512 + tid;
    float2 x[8];
#pragma unroll
    for (int q = 0; q < 4; ++q) x[q] = unpackbf2(row32[j + q * 1024]);
    x[4] = x[5] = x[6] = x[7] = float2{0.f, 0.f};  // const-folded through dft8
    dft8<-1>(x);
    float sn, cs;
    __sincosf(-6.2831853071795864769f / 8192.0f * (float)j, &sn, &cs);
    float2 w{cs, sn}, wq = w;
    x[1] = cmulf(x[1], wq);
#pragma unroll
    for (int q = 2; q < 8; ++q) {
      wq = cmulf(wq, w);
      x[q] = cmulf(x[q], wq);
    }
    float2* p = a + (j + (j >> 4));
#pragma unroll
    for (int q = 0; q < 8; ++q) p[q * 1088] = x[q];
  }
}

// Fused middle: forward radix-2 (h=1) + pointwise *W2 + inverse radix-2 (h=1)
__device__ __forceinline__ void mid_fused(float2* a, const uint32_t* __restrict__ wrow, int tid) {
  __syncthreads();
#pragma unroll
  for (int jj = 0; jj < 8; ++jj) {
    int j = jj * 512 + tid;
    float2* p = a + (2 * j + ((2 * j) >> 4));
    float2 u = p[0], v = p[1];
    float2 s{u.x + v.x, u.y + v.y}, dd{u.x - v.x, u.y - v.y};
    uint2 wv = *(const uint2*)(wrow + 2 * j);
    s = cmulf(s, unpackbf2(wv.x));
    dd = cmulf(dd, unpackbf2(wv.y));
    p[0] = float2{s.x + dd.x, s.y + dd.y};
    p[1] = float2{s.x - dd.x, s.y - dd.y};
  }
}

// Fused last inverse pass (h=1024): pack bf16 + store; keep only first 4096 outputs.
__device__ __forceinline__ void last_fused(float2* a, uint32_t* __restrict__ out32, int tid) {
  __syncthreads();
#pragma unroll
  for (int jj = 0; jj < 2; ++jj) {
    int j = jj * 512 + tid;
    float2* p = a + (j + (j >> 4));
    float2 x[8];
#pragma unroll
    for (int q = 0; q < 8; ++q) x[q] = p[q * 1088];
    float sn, cs;
    __sincosf(6.2831853071795864769f / 8192.0f * (float)j, &sn, &cs);
    float2 w{cs, sn}, wq = w;
    x[1] = cmulf(x[1], wq);
#pragma unroll
    for (int q = 2; q < 8; ++q) {
      wq = cmulf(wq, w);
      x[q] = cmulf(x[q], wq);
    }
    dft8<1>(x);
#pragma unroll
    for (int q = 0; q < 4; ++q) out32[j + q * 1024] = packbf2(x[q].x, x[q].y);
  }
}

// Phi2[k][f] = fwd-FFT( pad( (2/8192) * phi[2r, k], r<4096 ) ), scrambled order (matches k_conv)
__global__ __launch_bounds__(256) void k_phi(const float* __restrict__ phi,
                                             float2* __restrict__ Phi2) {
  extern __shared__ float2 buf[];
  int k = blockIdx.x, tid = threadIdx.x;
  const float scale = 2.0f / 8192.0f;
  for (int r = tid; r < 4096; r += 256) {
    buf[r + (r >> 4)] = float2{phi[(2 * r) * K_F + k] * scale, 0.0f};
    int r2i = r + 4096;
    buf[r2i + (r2i >> 4)] = float2{0.0f, 0.0f};
  }
  pass_r8<10, -1, 256>(buf, tid);
  pass_r8<7, -1, 256>(buf, tid);
  pass_r8<4, -1, 256>(buf, tid);
  pass_r8<1, -1, 256>(buf, tid);
  __syncthreads();
  for (int j = tid; j < 4096; j += 256) {  // forward radix-2 (h=1)
    float2* p = buf + (2 * j + ((2 * j) >> 4));
    float2 u = p[0], v = p[1];
    p[0] = float2{u.x + v.x, u.y + v.y};
    p[1] = float2{u.x - v.x, u.y - v.y};
  }
  __syncthreads();
  for (int f = tid; f < NFFT2; f += 256) Phi2[k * NFFT2 + f] = buf[f + (f >> 4)];
}

// W2[d][f] = sum_k Mf[k][d] * Phi2[k][f]  (packed bf16 re|im)
__global__ __launch_bounds__(256) void k_w2(const float2* __restrict__ Phi2,
                                            const float* __restrict__ Mf,
                                            uint32_t* __restrict__ W2) {
  __shared__ float2 p[K_F][256];
  __shared__ float mf[K_F][32];
  int tid = threadIdx.x;
  int fc = blockIdx.x & 31, dc = blockIdx.x >> 5;
  int f0 = fc * 256, d0 = dc * 32;
  for (int i = tid; i < K_F * 256; i += 256) {
    int k = i >> 8, fl = i & 255;
    p[k][fl] = Phi2[k * NFFT2 + f0 + fl];
  }
  for (int i = tid; i < K_F * 32; i += 256) {
    int k = i >> 5, dl = i & 31;
    mf[k][dl] = Mf[k * D_CH + d0 + dl];
  }
  __syncthreads();
  for (int dl = 0; dl < 32; ++dl) {
    float re = 0.f, im = 0.f;
#pragma unroll
    for (int k = 0; k < K_F; ++k) {
      float m = mf[k][dl];
      re += m * p[k][tid].x;
      im += m * p[k][tid].y;
    }
    W2[(size_t)(d0 + dl) * NFFT2 + f0 + tid] = packbf2(re, im);
  }
}

// ---------- bf16 MFMA GEMM (A read fp32 + converted in-staging): Cp[b][n][t] ----------
__device__ __forceinline__ void gload_lds16(const void* g, void* l) {
  __builtin_amdgcn_global_load_lds(
      (const __attribute__((address_space(1))) void*)g,
      (__attribute__((address_space(3))) void*)l, 16, 0, 0);
}

__global__ __launch_bounds__(256) void k_gemm(const float* __restrict__ X,
                                              const uint16_t* __restrict__ MiT,
                                              uint16_t* __restrict__ Cp) {
  __shared__ uint16_t As[128 * 64];  // [row m][64 k] bf16, XOR-swizzled storage
  __shared__ uint16_t Bs[128 * 64];  // [row n][64 k]
  int tid = threadIdx.x;
  int lane = tid & 63, wid = tid >> 6;
  int bm = blockIdx.x / 6, bn = blockIdx.x % 6;
  int m0 = bm * 128, n0 = bn * 128;
  int wr = wid >> 1, wc = wid & 1;
  int lm = lane & 15, lg = lane >> 4;
  f32x4 acc[4][4] = {};

  for (int kt = 0; kt < 12; ++kt) {
    int k0 = kt * 64;
    __syncthreads();
#pragma unroll
    for (int it = 0; it < 4; ++it) {  // stage B first: async global->LDS, no reg deps
      int s = it * 256 + tid;
      int row = s >> 3;
      int cb = ((s & 7) << 4) ^ ((row & 7) << 4);  // inverse-swizzled global col (bytes)
      gload_lds16(MiT + (size_t)(n0 + row) * 768 + k0 + (cb >> 1),
                  (char*)Bs + (it * 256 + wid * 64) * 16);
    }
#pragma unroll
    for (int it = 0; it < 4; ++it) {  // stage A: fp32 load -> cvt_pk bf16 -> swizzled ds_write
      int s = it * 256 + tid;
      int row = s >> 3, c16 = s & 7;
      const float* src = X + (size_t)(m0 + row) * 768 + k0 + c16 * 8;
      float4 f0 = *(const float4*)src;
      float4 f1 = *(const float4*)(src + 4);
      uint4 o;
      o.x = pkbf(f0.x, f0.y);
      o.y = pkbf(f0.z, f0.w);
      o.z = pkbf(f1.x, f1.y);
      o.w = pkbf(f1.z, f1.w);
      *(uint4*)((char*)As + row * 128 + ((c16 << 4) ^ ((row & 7) << 4))) = o;
    }
    asm volatile("s_waitcnt vmcnt(0)" ::: "memory");
    __syncthreads();
#pragma unroll
    for (int ks = 0; ks < 2; ++ks) {
      int kbyte = (ks * 32 + lg * 8) * 2;
      bf16x8 a[4], b[4];
#pragma unroll
      for (int mi = 0; mi < 4; ++mi) {
        int row = wr * 64 + mi * 16 + lm;
        a[mi] = *(const bf16x8*)((const char*)As + row * 128 + (kbyte ^ ((row & 7) << 4)));
      }
#pragma unroll
      for (int ni = 0; ni < 4; ++ni) {
        int row = wc * 64 + ni * 16 + lm;
        b[ni] = *(const bf16x8*)((const char*)Bs + row * 128 + (kbyte ^ ((row & 7) << 4)));
      }
#pragma unroll
      for (int mi = 0; mi < 4; ++mi)
#pragma unroll
        for (int ni = 0; ni < 4; ++ni)
          acc[mi][ni] = __builtin_amdgcn_mfma_f32_16x16x32_bf16(a[mi], b[ni], acc[mi][ni], 0, 0, 0);
    }
  }
  // epilogue: write transposed (B,D,L) bf16, 4 t-contig per lane
#pragma unroll
  for (int mi = 0; mi < 4; ++mi) {
#pragma unroll
    for (int ni = 0; ni < 4; ++ni) {
      int mg = m0 + wr * 64 + mi * 16 + lg * 4;
      int dd = n0 + wc * 64 + ni * 16 + lm;
      int bb = mg >> 13, t = mg & 8191;
      f32x4 v = acc[mi][ni];
      uint2 o;
      o.x = packbf2(v[0], v[1]);
      o.y = packbf2(v[2], v[3]);
      *(uint2*)(Cp + ((size_t)bb * 768 + dd) * 8192 + t) = o;
    }
  }
}

// ---------- per-(b,d) FFT conv: fused-load FFT, *W2, IFFT, fused pack-store ----------
__global__ __launch_bounds__(512, 4) void k_conv(const uint16_t* __restrict__ xprojT,
                                                 const uint32_t* __restrict__ W2,
                                                 uint16_t* __restrict__ convo) {
  extern __shared__ float2 buf[];
  int tid = threadIdx.x;
  int bd = blockIdx.x;  // b*768 + d
  int d = bd % 768;
  const uint32_t* row32 = (const uint32_t*)(xprojT + (size_t)bd * 8192);
  p1_fused(buf, row32, tid);
  pass_r8<7, -1, 512>(buf, tid);
  pass_r8<4, -1, 512>(buf, tid);
  pass_r8<1, -1, 512>(buf, tid);
  mid_fused(buf, W2 + (size_t)d * NFFT2, tid);
  pass_r8<1, 1, 512>(buf, tid);
  pass_r8<4, 1, 512>(buf, tid);
  pass_r8<7, 1, 512>(buf, tid);
  last_fused(buf, (uint32_t*)(convo + (size_t)bd * 8192), tid);
}

// ---------- transpose (B,D,L) bf16 -> (B,L,D) fp32 ----------
__global__ __launch_bounds__(256) void k_tr(const uint16_t* __restrict__ convo,
                                            float* __restrict__ out) {
  __shared__ uint16_t tile[64][72];
  int tid = threadIdx.x;
  int bx = blockIdx.x;
  int b = bx / 1536;
  int r = bx - b * 1536;
  int d0 = (r >> 7) << 6;
  int t0 = (r & 127) << 6;
  {
    int rr = tid >> 3;
    int c8 = (tid & 7) << 3;
#pragma unroll
    for (int p = 0; p < 2; ++p) {
      int row = p * 32 + rr;
      uint4 v = *(const uint4*)(convo + ((size_t)(b * 768 + d0 + row)) * 8192 + t0 + c8);
      *(uint4*)&tile[row][c8] = v;
    }
  }
  __syncthreads();
  {
    int c4 = (tid & 15) << 2;
    int tg = tid >> 4;
#pragma unroll
    for (int p = 0; p < 4; ++p) {
      int tt = p * 16 + tg;
      float4 o;
      o.x = __uint_as_float((uint32_t)tile[c4 + 0][tt] << 16);
      o.y = __uint_as_float((uint32_t)tile[c4 + 1][tt] << 16);
      o.z = __uint_as_float((uint32_t)tile[c4 + 2][tt] << 16);
      o.w = __uint_as_float((uint32_t)tile[c4 + 3][tt] << 16);
      *(float4*)(out + ((size_t)b * 8192 + t0 + tt) * 768 + d0 + c4) = o;
    }
  }
}

extern "C" void kernel_launch(void* const* d_in, const int* in_sizes, int n_in,
                              void* d_out, int out_size, void* d_ws, size_t ws_size,
                              hipStream_t stream) {
  const float* x   = (const float*)d_in[0];
  const float* phi = (const float*)d_in[1];
  const float* Mi  = (const float*)d_in[2];
  const float* Mf  = (const float*)d_in[3];
  float* out = (float*)d_out;

  // d_out doubles as staging: [48MB,96MB) x_projT bf16 (B,D,L); [0,48MB) unused until k_tr
  uint16_t* xprojT = (uint16_t*)d_out + 25165824;

  char* ws = (char*)d_ws;
  uint16_t* convo = (uint16_t*)ws;               // 50,331,648 B  (B,D,L) bf16 conv result
  uint32_t* W2    = (uint32_t*)(ws + 50331648);  // 25,165,824 B  [768][8192] bf16 re|im
  float2*   Phi2  = (float2*)(ws + 75497472);    //  1,572,864 B  [24][8192] fp32 complex
  uint16_t* MiT   = (uint16_t*)(ws + 77070336);  //  1,179,648 B  [768][768] bf16

  k_mit<<<2304, 256, 0, stream>>>(Mi, MiT);
  k_phi<<<24, 256, LDS_BYTES, stream>>>(phi, Phi2);
  k_w2<<<768, 256, 0, stream>>>(Phi2, Mf, W2);
  k_gemm<<<1536, 256, 0, stream>>>(x, MiT, xprojT);
  k_conv<<<3072, 512, LDS_BYTES, stream>>>(xprojT, W2, convo);
  k_tr<<<6144, 256, 0, stream>>>(convo, out);
}

// Round 4
// 236.471 us; speedup vs baseline: 1.8754x; 1.0708x over previous
//
#include <hip/hip_runtime.h>
#include <stdint.h>

// Problem constants
#define B_SZ 4
#define L_SEQ 8192
#define D_CH 768
#define K_F 24
#define NFFT2 8192     // FFT size after parity split (2*4096)
#define LDS_BYTES 69632  // 8704 float2 (padded: phi(i) = i + (i>>4))

typedef __attribute__((ext_vector_type(4))) float f32x4;
typedef __attribute__((ext_vector_type(8))) __bf16 bf16x8;

// ---------- bf16 helpers (RNE) ----------
__device__ __forceinline__ uint32_t f2bf1(float f) {
  uint32_t u = __float_as_uint(f);
  return (u + 0x7fffu + ((u >> 16) & 1u)) >> 16;
}
__device__ __forceinline__ uint32_t packbf2(float lo, float hi) {
  return f2bf1(lo) | (f2bf1(hi) << 16);
}
__device__ __forceinline__ float2 unpackbf2(uint32_t v) {
  return float2{__uint_as_float(v << 16), __uint_as_float(v & 0xffff0000u)};
}
__device__ __forceinline__ float2 cmulf(float2 a, float2 b) {
  return float2{a.x * b.x - a.y * b.y, a.x * b.y + a.y * b.x};
}
__device__ __forceinline__ uint32_t pkbf(float lo, float hi) {
  uint32_t r;
  asm("v_cvt_pk_bf16_f32 %0, %1, %2" : "=v"(r) : "v"(lo), "v"(hi));
  return r;
}

// MiT[n][e] = Mi[e][n], bf16
__global__ __launch_bounds__(256) void k_mit(const float* __restrict__ Mi,
                                             uint16_t* __restrict__ MiT) {
  int i = blockIdx.x * 256 + threadIdx.x;  // = n*768 + e
  int n = i / 768, e = i - n * 768;
  MiT[i] = (uint16_t)f2bf1(Mi[e * 768 + n]);
}

// ---------- radix-8 DFT building block ----------
// S=-1: forward (W8 = e^{-2pi i/8}); S=+1: inverse (unnormalized, W8^{-1})
template <int S>
__device__ __forceinline__ void dft8(float2* x) {
  const float C = 0.70710678118654752f;
  float2 t0{x[0].x + x[4].x, x[0].y + x[4].y}, t1{x[0].x - x[4].x, x[0].y - x[4].y};
  float2 t2{x[2].x + x[6].x, x[2].y + x[6].y}, t3{x[2].x - x[6].x, x[2].y - x[6].y};
  float2 t4{x[1].x + x[5].x, x[1].y + x[5].y}, t5{x[1].x - x[5].x, x[1].y - x[5].y};
  float2 t6{x[3].x + x[7].x, x[3].y + x[7].y}, t7{x[3].x - x[7].x, x[3].y - x[7].y};
  float2 t3r = (S < 0) ? float2{t3.y, -t3.x} : float2{-t3.y, t3.x};
  float2 t7r = (S < 0) ? float2{t7.y, -t7.x} : float2{-t7.y, t7.x};
  float2 e0{t0.x + t2.x, t0.y + t2.y}, e2{t0.x - t2.x, t0.y - t2.y};
  float2 e1{t1.x + t3r.x, t1.y + t3r.y}, e3{t1.x - t3r.x, t1.y - t3r.y};
  float2 o0{t4.x + t6.x, t4.y + t6.y}, o2{t4.x - t6.x, t4.y - t6.y};
  float2 o1{t5.x + t7r.x, t5.y + t7r.y}, o3{t5.x - t7r.x, t5.y - t7r.y};
  float2 o1r = (S < 0) ? float2{C * (o1.x + o1.y), C * (o1.y - o1.x)}
                       : float2{C * (o1.x - o1.y), C * (o1.y + o1.x)};
  float2 o2r = (S < 0) ? float2{o2.y, -o2.x} : float2{-o2.y, o2.x};
  float2 o3r = (S < 0) ? float2{C * (o3.y - o3.x), -C * (o3.x + o3.y)}
                       : float2{-C * (o3.x + o3.y), C * (o3.x - o3.y)};
  x[0] = float2{e0.x + o0.x, e0.y + o0.y};
  x[4] = float2{e0.x - o0.x, e0.y - o0.y};
  x[1] = float2{e1.x + o1r.x, e1.y + o1r.y};
  x[5] = float2{e1.x - o1r.x, e1.y - o1r.y};
  x[2] = float2{e2.x + o2r.x, e2.y + o2r.y};
  x[6] = float2{e2.x - o2r.x, e2.y - o2r.y};
  x[3] = float2{e3.x + o3r.x, e3.y + o3r.y};
  x[7] = float2{e3.x - o3r.x, e3.y - o3r.y};
}

// Generic radix-8 LDS pass on padded layout. One address compute per butterfly;
// all 16 LDS accesses use compile-time immediate offsets (stride st = h + h/16).
template <int LH, int S, int NT>
__device__ __forceinline__ void pass_r8(float2* a, int tid) {
  constexpr int h = 1 << LH;
  constexpr int st = h + (h >> 4);
  const float ang = (S < 0 ? -6.2831853071795864769f : 6.2831853071795864769f) / (float)(h * 8);
  __syncthreads();
#pragma unroll
  for (int jj = 0; jj < 1024 / NT; ++jj) {
    int j = jj * NT + tid;
    int pos = j & (h - 1);
    int base = ((j >> LH) << (LH + 3)) + pos;
    float2* p = a + (base + (base >> 4));
    float2 x[8];
#pragma unroll
    for (int q = 0; q < 8; ++q) x[q] = p[q * st];
    float sn, cs;
    __sincosf(ang * (float)pos, &sn, &cs);
    float2 w{cs, sn};
    if constexpr (S < 0) {
      dft8<-1>(x);
      float2 wq = w;
      x[1] = cmulf(x[1], wq);
#pragma unroll
      for (int q = 2; q < 8; ++q) {
        wq = cmulf(wq, w);
        x[q] = cmulf(x[q], wq);
      }
    } else {
      float2 wq = w;
      x[1] = cmulf(x[1], wq);
#pragma unroll
      for (int q = 2; q < 8; ++q) {
        wq = cmulf(wq, w);
        x[q] = cmulf(x[q], wq);
      }
      dft8<1>(x);
    }
#pragma unroll
    for (int q = 0; q < 8; ++q) p[q * st] = x[q];
  }
}

// Fused first forward pass (h=1024): read packed bf16 row from global, upper half zero.
__device__ __forceinline__ void p1_fused(float2* a, const uint32_t* __restrict__ row32, int tid) {
#pragma unroll
  for (int jj = 0; jj < 2; ++jj) {
    int j = jj * 512 + tid;
    float2 x[8];
#pragma unroll
    for (int q = 0; q < 4; ++q) x[q] = unpackbf2(row32[j + q * 1024]);
    x[4] = x[5] = x[6] = x[7] = float2{0.f, 0.f};  // const-folded through dft8
    dft8<-1>(x);
    float sn, cs;
    __sincosf(-6.2831853071795864769f / 8192.0f * (float)j, &sn, &cs);
    float2 w{cs, sn}, wq = w;
    x[1] = cmulf(x[1], wq);
#pragma unroll
    for (int q = 2; q < 8; ++q) {
      wq = cmulf(wq, w);
      x[q] = cmulf(x[q], wq);
    }
    float2* p = a + (j + (j >> 4));
#pragma unroll
    for (int q = 0; q < 8; ++q) p[q * 1088] = x[q];
  }
}

// Fused middle: forward radix-2 (h=1) + pointwise *W2 + inverse radix-2 (h=1)
__device__ __forceinline__ void mid_fused(float2* a, const uint32_t* __restrict__ wrow, int tid) {
  __syncthreads();
#pragma unroll
  for (int jj = 0; jj < 8; ++jj) {
    int j = jj * 512 + tid;
    float2* p = a + (2 * j + ((2 * j) >> 4));
    float2 u = p[0], v = p[1];
    float2 s{u.x + v.x, u.y + v.y}, dd{u.x - v.x, u.y - v.y};
    uint2 wv = *(const uint2*)(wrow + 2 * j);
    s = cmulf(s, unpackbf2(wv.x));
    dd = cmulf(dd, unpackbf2(wv.y));
    p[0] = float2{s.x + dd.x, s.y + dd.y};
    p[1] = float2{s.x - dd.x, s.y - dd.y};
  }
}

// Fused last inverse pass (h=1024): pack bf16 + store; keep only first 4096 outputs.
__device__ __forceinline__ void last_fused(float2* a, uint32_t* __restrict__ out32, int tid) {
  __syncthreads();
#pragma unroll
  for (int jj = 0; jj < 2; ++jj) {
    int j = jj * 512 + tid;
    float2* p = a + (j + (j >> 4));
    float2 x[8];
#pragma unroll
    for (int q = 0; q < 8; ++q) x[q] = p[q * 1088];
    float sn, cs;
    __sincosf(6.2831853071795864769f / 8192.0f * (float)j, &sn, &cs);
    float2 w{cs, sn}, wq = w;
    x[1] = cmulf(x[1], wq);
#pragma unroll
    for (int q = 2; q < 8; ++q) {
      wq = cmulf(wq, w);
      x[q] = cmulf(x[q], wq);
    }
    dft8<1>(x);
#pragma unroll
    for (int q = 0; q < 4; ++q) out32[j + q * 1024] = packbf2(x[q].x, x[q].y);
  }
}

// Phi2[k][f] = fwd-FFT( pad( (2/8192) * phi[2r, k], r<4096 ) ), scrambled order (matches k_conv)
__global__ __launch_bounds__(256) void k_phi(const float* __restrict__ phi,
                                             float2* __restrict__ Phi2) {
  extern __shared__ float2 buf[];
  int k = blockIdx.x, tid = threadIdx.x;
  const float scale = 2.0f / 8192.0f;
  for (int r = tid; r < 4096; r += 256) {
    buf[r + (r >> 4)] = float2{phi[(2 * r) * K_F + k] * scale, 0.0f};
    int r2i = r + 4096;
    buf[r2i + (r2i >> 4)] = float2{0.0f, 0.0f};
  }
  pass_r8<10, -1, 256>(buf, tid);
  pass_r8<7, -1, 256>(buf, tid);
  pass_r8<4, -1, 256>(buf, tid);
  pass_r8<1, -1, 256>(buf, tid);
  __syncthreads();
  for (int j = tid; j < 4096; j += 256) {  // forward radix-2 (h=1)
    float2* p = buf + (2 * j + ((2 * j) >> 4));
    float2 u = p[0], v = p[1];
    p[0] = float2{u.x + v.x, u.y + v.y};
    p[1] = float2{u.x - v.x, u.y - v.y};
  }
  __syncthreads();
  for (int f = tid; f < NFFT2; f += 256) Phi2[k * NFFT2 + f] = buf[f + (f >> 4)];
}

// W2[d][f] = sum_k Mf[k][d] * Phi2[k][f]  (packed bf16 re|im)
__global__ __launch_bounds__(256) void k_w2(const float2* __restrict__ Phi2,
                                            const float* __restrict__ Mf,
                                            uint32_t* __restrict__ W2) {
  __shared__ float2 p[K_F][256];
  __shared__ float mf[K_F][32];
  int tid = threadIdx.x;
  int fc = blockIdx.x & 31, dc = blockIdx.x >> 5;
  int f0 = fc * 256, d0 = dc * 32;
  for (int i = tid; i < K_F * 256; i += 256) {
    int k = i >> 8, fl = i & 255;
    p[k][fl] = Phi2[k * NFFT2 + f0 + fl];
  }
  for (int i = tid; i < K_F * 32; i += 256) {
    int k = i >> 5, dl = i & 31;
    mf[k][dl] = Mf[k * D_CH + d0 + dl];
  }
  __syncthreads();
  for (int dl = 0; dl < 32; ++dl) {
    float re = 0.f, im = 0.f;
#pragma unroll
    for (int k = 0; k < K_F; ++k) {
      float m = mf[k][dl];
      re += m * p[k][tid].x;
      im += m * p[k][tid].y;
    }
    W2[(size_t)(d0 + dl) * NFFT2 + f0 + tid] = packbf2(re, im);
  }
}

// ---------- bf16 MFMA GEMM, double-buffered, XCD-grouped: Cp[b][n][t] ----------
__device__ __forceinline__ void gload_lds16(const void* g, void* l) {
  __builtin_amdgcn_global_load_lds(
      (const __attribute__((address_space(1))) void*)g,
      (__attribute__((address_space(3))) void*)l, 16, 0, 0);
}

__global__ __launch_bounds__(256) void k_gemm(const float* __restrict__ X,
                                              const uint16_t* __restrict__ MiT,
                                              uint16_t* __restrict__ Cp) {
  __shared__ uint16_t As[2][128 * 64];  // [buf][row m][64 k] bf16, XOR-swizzled
  __shared__ uint16_t Bs[2][128 * 64];
  int tid = threadIdx.x;
  int lane = tid & 63, wid = tid >> 6;
  // bijective XCD swizzle: 1536 wg, 8 XCDs, 192/XCD; sibling bn-blocks share an XCD's L2
  int p = blockIdx.x;
  int v = (p & 7) * 192 + (p >> 3);
  int bm = v / 6, bn = v % 6;
  int m0 = bm * 128, n0 = bn * 128;
  int wr = wid >> 1, wc = wid & 1;
  int lm = lane & 15, lg = lane >> 4;
  f32x4 acc[4][4] = {};
  float4 fa[8];

  // --- staging helpers (unrolled, static indices) ---
#define LOAD_A(k0)                                                       \
  _Pragma("unroll") for (int it = 0; it < 4; ++it) {                     \
    int s = it * 256 + tid;                                              \
    int row = s >> 3, c16 = s & 7;                                       \
    const float* src = X + (size_t)(m0 + row) * 768 + (k0) + c16 * 8;    \
    fa[2 * it] = *(const float4*)src;                                    \
    fa[2 * it + 1] = *(const float4*)(src + 4);                          \
  }
#define STAGE_B(buf, k0)                                                 \
  _Pragma("unroll") for (int it = 0; it < 4; ++it) {                     \
    int s = it * 256 + tid;                                              \
    int row = s >> 3;                                                    \
    int cb = ((s & 7) << 4) ^ ((row & 7) << 4);                          \
    gload_lds16(MiT + (size_t)(n0 + row) * 768 + (k0) + (cb >> 1),       \
                (char*)Bs[buf] + (it * 256 + wid * 64) * 16);            \
  }
#define WRITE_A(buf)                                                     \
  _Pragma("unroll") for (int it = 0; it < 4; ++it) {                     \
    int s = it * 256 + tid;                                              \
    int row = s >> 3, c16 = s & 7;                                       \
    uint4 o;                                                             \
    o.x = pkbf(fa[2 * it].x, fa[2 * it].y);                              \
    o.y = pkbf(fa[2 * it].z, fa[2 * it].w);                              \
    o.z = pkbf(fa[2 * it + 1].x, fa[2 * it + 1].y);                      \
    o.w = pkbf(fa[2 * it + 1].z, fa[2 * it + 1].w);                      \
    *(uint4*)((char*)As[buf] + row * 128 + ((c16 << 4) ^ ((row & 7) << 4))) = o; \
  }

  // prologue: stage tile 0
  LOAD_A(0);
  STAGE_B(0, 0);
  WRITE_A(0);
  asm volatile("s_waitcnt vmcnt(0)" ::: "memory");
  __syncthreads();

  int cur = 0;
  for (int kt = 0; kt < 12; ++kt) {
    int k0n = (kt + 1) * 64;
    if (kt < 11) {  // issue next-tile loads early: HBM latency hides under MFMAs
      LOAD_A(k0n);
      STAGE_B(cur ^ 1, k0n);
    }
    // compute current tile
#pragma unroll
    for (int ks = 0; ks < 2; ++ks) {
      int kbyte = (ks * 32 + lg * 8) * 2;
      bf16x8 a[4], b[4];
#pragma unroll
      for (int mi = 0; mi < 4; ++mi) {
        int row = wr * 64 + mi * 16 + lm;
        a[mi] = *(const bf16x8*)((const char*)As[cur] + row * 128 + (kbyte ^ ((row & 7) << 4)));
      }
#pragma unroll
      for (int ni = 0; ni < 4; ++ni) {
        int row = wc * 64 + ni * 16 + lm;
        b[ni] = *(const bf16x8*)((const char*)Bs[cur] + row * 128 + (kbyte ^ ((row & 7) << 4)));
      }
#pragma unroll
      for (int mi = 0; mi < 4; ++mi)
#pragma unroll
        for (int ni = 0; ni < 4; ++ni)
          acc[mi][ni] = __builtin_amdgcn_mfma_f32_16x16x32_bf16(a[mi], b[ni], acc[mi][ni], 0, 0, 0);
    }
    if (kt < 11) WRITE_A(cur ^ 1);
    __syncthreads();  // drains lgkm (A ds_writes) + vmcnt (B gload_lds)
    cur ^= 1;
  }
#undef LOAD_A
#undef STAGE_B
#undef WRITE_A

  // epilogue: write transposed (B,D,L) bf16, 4 t-contig per lane
#pragma unroll
  for (int mi = 0; mi < 4; ++mi) {
#pragma unroll
    for (int ni = 0; ni < 4; ++ni) {
      int mg = m0 + wr * 64 + mi * 16 + lg * 4;
      int dd = n0 + wc * 64 + ni * 16 + lm;
      int bb = mg >> 13, t = mg & 8191;
      f32x4 vv = acc[mi][ni];
      uint2 o;
      o.x = packbf2(vv[0], vv[1]);
      o.y = packbf2(vv[2], vv[3]);
      *(uint2*)(Cp + ((size_t)bb * 768 + dd) * 8192 + t) = o;
    }
  }
}

// ---------- per-(b,d) FFT conv: fused-load FFT, *W2, IFFT, fused pack-store ----------
__global__ __launch_bounds__(512, 4) void k_conv(const uint16_t* __restrict__ xprojT,
                                                 const uint32_t* __restrict__ W2,
                                                 uint16_t* __restrict__ convo) {
  extern __shared__ float2 buf[];
  int tid = threadIdx.x;
  int bd = blockIdx.x;  // b*768 + d
  int d = bd % 768;
  const uint32_t* row32 = (const uint32_t*)(xprojT + (size_t)bd * 8192);
  p1_fused(buf, row32, tid);
  pass_r8<7, -1, 512>(buf, tid);
  pass_r8<4, -1, 512>(buf, tid);
  pass_r8<1, -1, 512>(buf, tid);
  mid_fused(buf, W2 + (size_t)d * NFFT2, tid);
  pass_r8<1, 1, 512>(buf, tid);
  pass_r8<4, 1, 512>(buf, tid);
  pass_r8<7, 1, 512>(buf, tid);
  last_fused(buf, (uint32_t*)(convo + (size_t)bd * 8192), tid);
}

// ---------- transpose (B,D,L) bf16 -> (B,L,D) fp32 ----------
__global__ __launch_bounds__(256) void k_tr(const uint16_t* __restrict__ convo,
                                            float* __restrict__ out) {
  __shared__ uint16_t tile[64][72];
  int tid = threadIdx.x;
  int bx = blockIdx.x;
  int b = bx / 1536;
  int r = bx - b * 1536;
  int d0 = (r >> 7) << 6;
  int t0 = (r & 127) << 6;
  {
    int rr = tid >> 3;
    int c8 = (tid & 7) << 3;
#pragma unroll
    for (int p = 0; p < 2; ++p) {
      int row = p * 32 + rr;
      uint4 v = *(const uint4*)(convo + ((size_t)(b * 768 + d0 + row)) * 8192 + t0 + c8);
      *(uint4*)&tile[row][c8] = v;
    }
  }
  __syncthreads();
  {
    int c4 = (tid & 15) << 2;
    int tg = tid >> 4;
#pragma unroll
    for (int p = 0; p < 4; ++p) {
      int tt = p * 16 + tg;
      float4 o;
      o.x = __uint_as_float((uint32_t)tile[c4 + 0][tt] << 16);
      o.y = __uint_as_float((uint32_t)tile[c4 + 1][tt] << 16);
      o.z = __uint_as_float((uint32_t)tile[c4 + 2][tt] << 16);
      o.w = __uint_as_float((uint32_t)tile[c4 + 3][tt] << 16);
      *(float4*)(out + ((size_t)b * 8192 + t0 + tt) * 768 + d0 + c4) = o;
    }
  }
}

extern "C" void kernel_launch(void* const* d_in, const int* in_sizes, int n_in,
                              void* d_out, int out_size, void* d_ws, size_t ws_size,
                              hipStream_t stream) {
  const float* x   = (const float*)d_in[0];
  const float* phi = (const float*)d_in[1];
  const float* Mi  = (const float*)d_in[2];
  const float* Mf  = (const float*)d_in[3];
  float* out = (float*)d_out;

  // d_out doubles as staging: [48MB,96MB) x_projT bf16 (B,D,L); [0,48MB) unused until k_tr
  uint16_t* xprojT = (uint16_t*)d_out + 25165824;

  char* ws = (char*)d_ws;
  uint16_t* convo = (uint16_t*)ws;               // 50,331,648 B  (B,D,L) bf16 conv result
  uint32_t* W2    = (uint32_t*)(ws + 50331648);  // 25,165,824 B  [768][8192] bf16 re|im
  float2*   Phi2  = (float2*)(ws + 75497472);    //  1,572,864 B  [24][8192] fp32 complex
  uint16_t* MiT   = (uint16_t*)(ws + 77070336);  //  1,179,648 B  [768][768] bf16

  k_mit<<<2304, 256, 0, stream>>>(Mi, MiT);
  k_phi<<<24, 256, LDS_BYTES, stream>>>(phi, Phi2);
  k_w2<<<768, 256, 0, stream>>>(Phi2, Mf, W2);
  k_gemm<<<1536, 256, 0, stream>>>(x, MiT, xprojT);
  k_conv<<<3072, 512, LDS_BYTES, stream>>>(xprojT, W2, convo);
  k_tr<<<6144, 256, 0, stream>>>(convo, out);
}

// Round 5
// 230.088 us; speedup vs baseline: 1.9274x; 1.0277x over previous
//
#include <hip/hip_runtime.h>
#include <stdint.h>

// Problem constants
#define B_SZ 4
#define L_SEQ 8192
#define D_CH 768
#define K_F 24
#define NFFT2 8192     // FFT size after parity split (2*4096)
#define LDS_BYTES 69632  // 8704 float2 (padded: phi(i) = i + (i>>4))
#define GEMM_LDS 98304   // As 2x16KB + Bs 2x32KB

typedef __attribute__((ext_vector_type(4))) float f32x4;
typedef __attribute__((ext_vector_type(8))) __bf16 bf16x8;

// ---------- bf16 helpers (RNE) ----------
__device__ __forceinline__ uint32_t f2bf1(float f) {
  uint32_t u = __float_as_uint(f);
  return (u + 0x7fffu + ((u >> 16) & 1u)) >> 16;
}
__device__ __forceinline__ uint32_t packbf2(float lo, float hi) {
  return f2bf1(lo) | (f2bf1(hi) << 16);
}
__device__ __forceinline__ float2 unpackbf2(uint32_t v) {
  return float2{__uint_as_float(v << 16), __uint_as_float(v & 0xffff0000u)};
}
__device__ __forceinline__ float2 cmulf(float2 a, float2 b) {
  return float2{a.x * b.x - a.y * b.y, a.x * b.y + a.y * b.x};
}
__device__ __forceinline__ uint32_t pkbf(float lo, float hi) {
  uint32_t r;
  asm("v_cvt_pk_bf16_f32 %0, %1, %2" : "=v"(r) : "v"(lo), "v"(hi));
  return r;
}

// MiT[n][e] = Mi[e][n], bf16
__global__ __launch_bounds__(256) void k_mit(const float* __restrict__ Mi,
                                             uint16_t* __restrict__ MiT) {
  int i = blockIdx.x * 256 + threadIdx.x;  // = n*768 + e
  int n = i / 768, e = i - n * 768;
  MiT[i] = (uint16_t)f2bf1(Mi[e * 768 + n]);
}

// ---------- radix-8 DFT building block ----------
// S=-1: forward (W8 = e^{-2pi i/8}); S=+1: inverse (unnormalized, W8^{-1})
template <int S>
__device__ __forceinline__ void dft8(float2* x) {
  const float C = 0.70710678118654752f;
  float2 t0{x[0].x + x[4].x, x[0].y + x[4].y}, t1{x[0].x - x[4].x, x[0].y - x[4].y};
  float2 t2{x[2].x + x[6].x, x[2].y + x[6].y}, t3{x[2].x - x[6].x, x[2].y - x[6].y};
  float2 t4{x[1].x + x[5].x, x[1].y + x[5].y}, t5{x[1].x - x[5].x, x[1].y - x[5].y};
  float2 t6{x[3].x + x[7].x, x[3].y + x[7].y}, t7{x[3].x - x[7].x, x[3].y - x[7].y};
  float2 t3r = (S < 0) ? float2{t3.y, -t3.x} : float2{-t3.y, t3.x};
  float2 t7r = (S < 0) ? float2{t7.y, -t7.x} : float2{-t7.y, t7.x};
  float2 e0{t0.x + t2.x, t0.y + t2.y}, e2{t0.x - t2.x, t0.y - t2.y};
  float2 e1{t1.x + t3r.x, t1.y + t3r.y}, e3{t1.x - t3r.x, t1.y - t3r.y};
  float2 o0{t4.x + t6.x, t4.y + t6.y}, o2{t4.x - t6.x, t4.y - t6.y};
  float2 o1{t5.x + t7r.x, t5.y + t7r.y}, o3{t5.x - t7r.x, t5.y - t7r.y};
  float2 o1r = (S < 0) ? float2{C * (o1.x + o1.y), C * (o1.y - o1.x)}
                       : float2{C * (o1.x - o1.y), C * (o1.y + o1.x)};
  float2 o2r = (S < 0) ? float2{o2.y, -o2.x} : float2{-o2.y, o2.x};
  float2 o3r = (S < 0) ? float2{C * (o3.y - o3.x), -C * (o3.x + o3.y)}
                       : float2{-C * (o3.x + o3.y), C * (o3.x - o3.y)};
  x[0] = float2{e0.x + o0.x, e0.y + o0.y};
  x[4] = float2{e0.x - o0.x, e0.y - o0.y};
  x[1] = float2{e1.x + o1r.x, e1.y + o1r.y};
  x[5] = float2{e1.x - o1r.x, e1.y - o1r.y};
  x[2] = float2{e2.x + o2r.x, e2.y + o2r.y};
  x[6] = float2{e2.x - o2r.x, e2.y - o2r.y};
  x[3] = float2{e3.x + o3r.x, e3.y + o3r.y};
  x[7] = float2{e3.x - o3r.x, e3.y - o3r.y};
}

// Generic radix-8 LDS pass on padded layout. One address compute per butterfly;
// all 16 LDS accesses use compile-time immediate offsets (stride st = h + h/16).
template <int LH, int S, int NT>
__device__ __forceinline__ void pass_r8(float2* a, int tid) {
  constexpr int h = 1 << LH;
  constexpr int st = h + (h >> 4);
  const float ang = (S < 0 ? -6.2831853071795864769f : 6.2831853071795864769f) / (float)(h * 8);
  __syncthreads();
#pragma unroll
  for (int jj = 0; jj < 1024 / NT; ++jj) {
    int j = jj * NT + tid;
    int pos = j & (h - 1);
    int base = ((j >> LH) << (LH + 3)) + pos;
    float2* p = a + (base + (base >> 4));
    float2 x[8];
#pragma unroll
    for (int q = 0; q < 8; ++q) x[q] = p[q * st];
    float sn, cs;
    __sincosf(ang * (float)pos, &sn, &cs);
    float2 w{cs, sn};
    if constexpr (S < 0) {
      dft8<-1>(x);
      float2 wq = w;
      x[1] = cmulf(x[1], wq);
#pragma unroll
      for (int q = 2; q < 8; ++q) {
        wq = cmulf(wq, w);
        x[q] = cmulf(x[q], wq);
      }
    } else {
      float2 wq = w;
      x[1] = cmulf(x[1], wq);
#pragma unroll
      for (int q = 2; q < 8; ++q) {
        wq = cmulf(wq, w);
        x[q] = cmulf(x[q], wq);
      }
      dft8<1>(x);
    }
#pragma unroll
    for (int q = 0; q < 8; ++q) p[q * st] = x[q];
  }
}

// Fused first forward pass (h=1024): read packed bf16 row from global, upper half zero.
__device__ __forceinline__ void p1_fused(float2* a, const uint32_t* __restrict__ row32, int tid) {
#pragma unroll
  for (int jj = 0; jj < 2; ++jj) {
    int j = jj * 512 + tid;
    float2 x[8];
#pragma unroll
    for (int q = 0; q < 4; ++q) x[q] = unpackbf2(row32[j + q * 1024]);
    x[4] = x[5] = x[6] = x[7] = float2{0.f, 0.f};  // const-folded through dft8
    dft8<-1>(x);
    float sn, cs;
    __sincosf(-6.2831853071795864769f / 8192.0f * (float)j, &sn, &cs);
    float2 w{cs, sn}, wq = w;
    x[1] = cmulf(x[1], wq);
#pragma unroll
    for (int q = 2; q < 8; ++q) {
      wq = cmulf(wq, w);
      x[q] = cmulf(x[q], wq);
    }
    float2* p = a + (j + (j >> 4));
#pragma unroll
    for (int q = 0; q < 8; ++q) p[q * 1088] = x[q];
  }
}

// Fused middle: forward radix-2 (h=1) + pointwise *W2 + inverse radix-2 (h=1)
__device__ __forceinline__ void mid_fused(float2* a, const uint32_t* __restrict__ wrow, int tid) {
  __syncthreads();
#pragma unroll
  for (int jj = 0; jj < 8; ++jj) {
    int j = jj * 512 + tid;
    float2* p = a + (2 * j + ((2 * j) >> 4));
    float2 u = p[0], v = p[1];
    float2 s{u.x + v.x, u.y + v.y}, dd{u.x - v.x, u.y - v.y};
    uint2 wv = *(const uint2*)(wrow + 2 * j);
    s = cmulf(s, unpackbf2(wv.x));
    dd = cmulf(dd, unpackbf2(wv.y));
    p[0] = float2{s.x + dd.x, s.y + dd.y};
    p[1] = float2{s.x - dd.x, s.y - dd.y};
  }
}

// Fused last inverse pass (h=1024): pack bf16 + store; keep only first 4096 outputs.
__device__ __forceinline__ void last_fused(float2* a, uint32_t* __restrict__ out32, int tid) {
  __syncthreads();
#pragma unroll
  for (int jj = 0; jj < 2; ++jj) {
    int j = jj * 512 + tid;
    float2* p = a + (j + (j >> 4));
    float2 x[8];
#pragma unroll
    for (int q = 0; q < 8; ++q) x[q] = p[q * 1088];
    float sn, cs;
    __sincosf(6.2831853071795864769f / 8192.0f * (float)j, &sn, &cs);
    float2 w{cs, sn}, wq = w;
    x[1] = cmulf(x[1], wq);
#pragma unroll
    for (int q = 2; q < 8; ++q) {
      wq = cmulf(wq, w);
      x[q] = cmulf(x[q], wq);
    }
    dft8<1>(x);
#pragma unroll
    for (int q = 0; q < 4; ++q) out32[j + q * 1024] = packbf2(x[q].x, x[q].y);
  }
}

// Phi2[k][f] = fwd-FFT( pad( (2/8192) * phi[2r, k], r<4096 ) ), scrambled order (matches k_conv)
__global__ __launch_bounds__(256) void k_phi(const float* __restrict__ phi,
                                             float2* __restrict__ Phi2) {
  extern __shared__ float2 buf[];
  int k = blockIdx.x, tid = threadIdx.x;
  const float scale = 2.0f / 8192.0f;
  for (int r = tid; r < 4096; r += 256) {
    buf[r + (r >> 4)] = float2{phi[(2 * r) * K_F + k] * scale, 0.0f};
    int r2i = r + 4096;
    buf[r2i + (r2i >> 4)] = float2{0.0f, 0.0f};
  }
  pass_r8<10, -1, 256>(buf, tid);
  pass_r8<7, -1, 256>(buf, tid);
  pass_r8<4, -1, 256>(buf, tid);
  pass_r8<1, -1, 256>(buf, tid);
  __syncthreads();
  for (int j = tid; j < 4096; j += 256) {  // forward radix-2 (h=1)
    float2* p = buf + (2 * j + ((2 * j) >> 4));
    float2 u = p[0], v = p[1];
    p[0] = float2{u.x + v.x, u.y + v.y};
    p[1] = float2{u.x - v.x, u.y - v.y};
  }
  __syncthreads();
  for (int f = tid; f < NFFT2; f += 256) Phi2[k * NFFT2 + f] = buf[f + (f >> 4)];
}

// W2[d][f] = sum_k Mf[k][d] * Phi2[k][f]  (packed bf16 re|im)
__global__ __launch_bounds__(256) void k_w2(const float2* __restrict__ Phi2,
                                            const float* __restrict__ Mf,
                                            uint32_t* __restrict__ W2) {
  __shared__ float2 p[K_F][256];
  __shared__ float mf[K_F][32];
  int tid = threadIdx.x;
  int fc = blockIdx.x & 31, dc = blockIdx.x >> 5;
  int f0 = fc * 256, d0 = dc * 32;
  for (int i = tid; i < K_F * 256; i += 256) {
    int k = i >> 8, fl = i & 255;
    p[k][fl] = Phi2[k * NFFT2 + f0 + fl];
  }
  for (int i = tid; i < K_F * 32; i += 256) {
    int k = i >> 5, dl = i & 31;
    mf[k][dl] = Mf[k * D_CH + d0 + dl];
  }
  __syncthreads();
  for (int dl = 0; dl < 32; ++dl) {
    float re = 0.f, im = 0.f;
#pragma unroll
    for (int k = 0; k < K_F; ++k) {
      float m = mf[k][dl];
      re += m * p[k][tid].x;
      im += m * p[k][tid].y;
    }
    W2[(size_t)(d0 + dl) * NFFT2 + f0 + tid] = packbf2(re, im);
  }
}

// ---------- bf16 MFMA GEMM, deep-pipelined 128x256 tile, 512 thr: Cp[b][n][t] ----------
__device__ __forceinline__ void gload_lds16(const void* g, void* l) {
  __builtin_amdgcn_global_load_lds(
      (const __attribute__((address_space(1))) void*)g,
      (__attribute__((address_space(3))) void*)l, 16, 0, 0);
}

__global__ __launch_bounds__(512, 2) void k_gemm(const float* __restrict__ X,
                                                 const uint16_t* __restrict__ MiT,
                                                 uint16_t* __restrict__ Cp) {
  extern __shared__ char lds[];
  // As: 2 x [128 rows][64 k] bf16 (16 KB each); Bs: 2 x [256 rows][64 k] (32 KB each)
  char* const As0 = lds;
  char* const Bs0 = lds + 32768;
  int tid = threadIdx.x;
  int lane = tid & 63, wid = tid >> 6;
  // bijective XCD swizzle: 768 wg = 8 XCD x 96; the 3 bn-siblings of a bm share one XCD L2
  int p = blockIdx.x;
  int v = (p & 7) * 96 + (p >> 3);
  int bm = v / 3, bn = v % 3;
  int m0 = bm * 128, n0 = bn * 256;
  int wr = wid >> 2, wc = wid & 3;  // 2 x 4 waves, per-wave output 64x64
  int lm = lane & 15, lg = lane >> 4;
  f32x4 acc[4][4] = {};
  float4 fa[4];

#define STAGE_B(bufc, k0)                                              \
  _Pragma("unroll") for (int it = 0; it < 4; ++it) {                   \
    int s = it * 512 + tid;                                            \
    int row = s >> 3;                                                  \
    int cb = ((s & 7) << 4) ^ ((row & 7) << 4);                        \
    gload_lds16(MiT + (size_t)(n0 + row) * 768 + (k0) + (cb >> 1),     \
                Bs0 + (bufc)*32768 + (it * 512 + wid * 64) * 16);      \
  }
#define LOAD_A(k0)                                                     \
  _Pragma("unroll") for (int jt = 0; jt < 2; ++jt) {                   \
    int s = jt * 512 + tid;                                            \
    int row = s >> 3, c16 = s & 7;                                     \
    const float* src = X + (size_t)(m0 + row) * 768 + (k0) + c16 * 8;  \
    fa[2 * jt] = *(const float4*)src;                                  \
    fa[2 * jt + 1] = *(const float4*)(src + 4);                        \
  }
#define WRITE_A(bufc)                                                  \
  _Pragma("unroll") for (int jt = 0; jt < 2; ++jt) {                   \
    int s = jt * 512 + tid;                                            \
    int row = s >> 3, c16 = s & 7;                                     \
    uint4 o;                                                           \
    o.x = pkbf(fa[2 * jt].x, fa[2 * jt].y);                            \
    o.y = pkbf(fa[2 * jt].z, fa[2 * jt].w);                            \
    o.z = pkbf(fa[2 * jt + 1].x, fa[2 * jt + 1].y);                    \
    o.w = pkbf(fa[2 * jt + 1].z, fa[2 * jt + 1].w);                    \
    *(uint4*)(As0 + (bufc)*16384 + row * 128 + ((c16 << 4) ^ ((row & 7) << 4))) = o; \
  }
#define RD_A(dst, bufc, kbyte)                                                         \
  _Pragma("unroll") for (int i = 0; i < 4; ++i) {                                      \
    int row = wr * 64 + i * 16 + lm;                                                   \
    dst[i] = *(const bf16x8*)(As0 + (bufc)*16384 + row * 128 + ((kbyte) ^ ((row & 7) << 4))); \
  }
#define RD_B(dst, bufc, kbyte)                                                         \
  _Pragma("unroll") for (int i = 0; i < 4; ++i) {                                      \
    int row = wc * 64 + i * 16 + lm;                                                   \
    dst[i] = *(const bf16x8*)(Bs0 + (bufc)*32768 + row * 128 + ((kbyte) ^ ((row & 7) << 4))); \
  }
#define MFMA16(av, bv)                                                        \
  _Pragma("unroll") for (int mi = 0; mi < 4; ++mi)                            \
  _Pragma("unroll") for (int ni = 0; ni < 4; ++ni)                            \
      acc[mi][ni] = __builtin_amdgcn_mfma_f32_16x16x32_bf16(av[mi], bv[ni], acc[mi][ni], 0, 0, 0);

  // prologue: stage tile 0
  STAGE_B(0, 0);
  LOAD_A(0);
  WRITE_A(0);
  asm volatile("s_waitcnt vmcnt(0) lgkmcnt(0)" ::: "memory");
  __builtin_amdgcn_s_barrier();

  int cur = 0;
  for (int kt = 0; kt < 12; ++kt) {
    int nxt = cur ^ 1, k0n = (kt + 1) * 64;
    int kb0 = lg * 16, kb1 = 64 + lg * 16;
    // ---- phase 0 (kslot 0): issue next-tile loads, then MFMA cluster ----
    if (kt < 11) {
      STAGE_B(nxt, k0n);
      LOAD_A(k0n);
    }
    {
      bf16x8 a0[4], b0[4];
      RD_A(a0, cur, kb0);
      RD_B(b0, cur, kb0);
      asm volatile("s_waitcnt lgkmcnt(0)" ::: "memory");
      __builtin_amdgcn_sched_barrier(0);
      __builtin_amdgcn_s_setprio(1);
      MFMA16(a0, b0);
      __builtin_amdgcn_s_setprio(0);
    }
    __builtin_amdgcn_s_barrier();
    // ---- phase 1 (kslot 1) ----
    {
      bf16x8 a1[4], b1[4];
      RD_A(a1, cur, kb1);
      RD_B(b1, cur, kb1);
      asm volatile("s_waitcnt lgkmcnt(0)" ::: "memory");
      __builtin_amdgcn_sched_barrier(0);
      __builtin_amdgcn_s_setprio(1);
      MFMA16(a1, b1);
      __builtin_amdgcn_s_setprio(0);
    }
    if (kt < 11) WRITE_A(nxt);  // compiler waits fa's vmcnt here (loads issued phase 0)
    asm volatile("s_waitcnt vmcnt(0) lgkmcnt(0)" ::: "memory");
    __builtin_amdgcn_s_barrier();
    cur = nxt;
  }
#undef STAGE_B
#undef LOAD_A
#undef WRITE_A
#undef RD_A
#undef RD_B
#undef MFMA16

  // epilogue: write transposed (B,D,L) bf16, 4 t-contig per lane
#pragma unroll
  for (int mi = 0; mi < 4; ++mi) {
#pragma unroll
    for (int ni = 0; ni < 4; ++ni) {
      int mg = m0 + wr * 64 + mi * 16 + lg * 4;
      int dd = n0 + wc * 64 + ni * 16 + lm;
      int bb = mg >> 13, t = mg & 8191;
      f32x4 vv = acc[mi][ni];
      uint2 o;
      o.x = packbf2(vv[0], vv[1]);
      o.y = packbf2(vv[2], vv[3]);
      *(uint2*)(Cp + ((size_t)bb * 768 + dd) * 8192 + t) = o;
    }
  }
}

// ---------- per-(b,d) FFT conv: fused-load FFT, *W2, IFFT, fused pack-store ----------
__global__ __launch_bounds__(512, 4) void k_conv(const uint16_t* __restrict__ xprojT,
                                                 const uint32_t* __restrict__ W2,
                                                 uint16_t* __restrict__ convo) {
  extern __shared__ float2 buf[];
  int tid = threadIdx.x;
  int bd = blockIdx.x;  // b*768 + d
  int d = bd % 768;
  const uint32_t* row32 = (const uint32_t*)(xprojT + (size_t)bd * 8192);
  p1_fused(buf, row32, tid);
  pass_r8<7, -1, 512>(buf, tid);
  pass_r8<4, -1, 512>(buf, tid);
  pass_r8<1, -1, 512>(buf, tid);
  mid_fused(buf, W2 + (size_t)d * NFFT2, tid);
  pass_r8<1, 1, 512>(buf, tid);
  pass_r8<4, 1, 512>(buf, tid);
  pass_r8<7, 1, 512>(buf, tid);
  last_fused(buf, (uint32_t*)(convo + (size_t)bd * 8192), tid);
}

// ---------- transpose (B,D,L) bf16 -> (B,L,D) fp32 ----------
__global__ __launch_bounds__(256) void k_tr(const uint16_t* __restrict__ convo,
                                            float* __restrict__ out) {
  __shared__ uint16_t tile[64][72];
  int tid = threadIdx.x;
  int bx = blockIdx.x;
  int b = bx / 1536;
  int r = bx - b * 1536;
  int d0 = (r >> 7) << 6;
  int t0 = (r & 127) << 6;
  {
    int rr = tid >> 3;
    int c8 = (tid & 7) << 3;
#pragma unroll
    for (int p = 0; p < 2; ++p) {
      int row = p * 32 + rr;
      uint4 v = *(const uint4*)(convo + ((size_t)(b * 768 + d0 + row)) * 8192 + t0 + c8);
      *(uint4*)&tile[row][c8] = v;
    }
  }
  __syncthreads();
  {
    int c4 = (tid & 15) << 2;
    int tg = tid >> 4;
#pragma unroll
    for (int p = 0; p < 4; ++p) {
      int tt = p * 16 + tg;
      float4 o;
      o.x = __uint_as_float((uint32_t)tile[c4 + 0][tt] << 16);
      o.y = __uint_as_float((uint32_t)tile[c4 + 1][tt] << 16);
      o.z = __uint_as_float((uint32_t)tile[c4 + 2][tt] << 16);
      o.w = __uint_as_float((uint32_t)tile[c4 + 3][tt] << 16);
      *(float4*)(out + ((size_t)b * 8192 + t0 + tt) * 768 + d0 + c4) = o;
    }
  }
}

extern "C" void kernel_launch(void* const* d_in, const int* in_sizes, int n_in,
                              void* d_out, int out_size, void* d_ws, size_t ws_size,
                              hipStream_t stream) {
  const float* x   = (const float*)d_in[0];
  const float* phi = (const float*)d_in[1];
  const float* Mi  = (const float*)d_in[2];
  const float* Mf  = (const float*)d_in[3];
  float* out = (float*)d_out;

  // d_out doubles as staging: [48MB,96MB) x_projT bf16 (B,D,L); [0,48MB) unused until k_tr
  uint16_t* xprojT = (uint16_t*)d_out + 25165824;

  char* ws = (char*)d_ws;
  uint16_t* convo = (uint16_t*)ws;               // 50,331,648 B  (B,D,L) bf16 conv result
  uint32_t* W2    = (uint32_t*)(ws + 50331648);  // 25,165,824 B  [768][8192] bf16 re|im
  float2*   Phi2  = (float2*)(ws + 75497472);    //  1,572,864 B  [24][8192] fp32 complex
  uint16_t* MiT   = (uint16_t*)(ws + 77070336);  //  1,179,648 B  [768][768] bf16

  k_mit<<<2304, 256, 0, stream>>>(Mi, MiT);
  k_phi<<<24, 256, LDS_BYTES, stream>>>(phi, Phi2);
  k_w2<<<768, 256, 0, stream>>>(Phi2, Mf, W2);
  k_gemm<<<768, 512, GEMM_LDS, stream>>>(x, MiT, xprojT);
  k_conv<<<3072, 512, LDS_BYTES, stream>>>(xprojT, W2, convo);
  k_tr<<<6144, 256, 0, stream>>>(convo, out);
}